// Round 8
// baseline (237.288 us; speedup 1.0000x reference)
//
#include <hip/hip_runtime.h>

// LightweightConv1d: y[b,t,c] = sum_k softmax(w)[c%H,k] * x[b, t+k-PAD, c]
// x: (B,T,C) fp32 contiguous (C innermost), w: (H,1,K) fp32, y: (B,T,C) fp32.
// Compulsory HBM ~200-268 MB -> 32-43 us. Harness fills ~154 us of every bench
// number; conv dispatch is the remainder.
// History (conv dispatch): R2 ~77 / R4 92.5 / R5 80.7 / R6 97 / R7 85.6 /
//   R8 wrong-results / R9 ~77 (LDS-staged, guaranteed depth-14).
//   R9 killed the MLP-depth theory: depth was provably 14, plateau held.
//   Remaining shared trait of all plateau kernels: drain-then-compute convoy
//   (vmcnt(0) before compute; memory pipe idle during compute, compute idle
//   during drain; VALUBusy ~8% can hide nothing -> ~50% stall).
// R10: persistent-strip LDS ring, wave-decoupled, counted vmcnt (T3/T4).
//   Block owns 64 rows; ring of 16 row-slots (64KB, 2 blocks/CU); steps of 4:
//   issue 4 global_load_lds (rows +7..+10, CLAMPED so VMEM count stays exact)
//   -> s_waitcnt vmcnt(8) (4 new loads + 4 prev stores; NEVER 0 in loop)
//   -> zero-fix OOB slots -> 10 ds_read_b128 -> 112 FMA -> 4 nt stores.
//   No __syncthreads anywhere: each wave stages/reads only its own quarter-row
//   (wave-private LDS) -> waves self-pace. Amp 1.75 -> 1.09 (halo lives in
//   ring). t0 % 16 == 0 -> all slot indices compile-time after unroll.

constexpr int B_    = 8;
constexpr int T_    = 4096;
constexpr int C_    = 1024;
constexpr int H_    = 16;
constexpr int K_    = 7;
constexpr int PAD_  = 3;
constexpr int STEP  = 4;              // output rows per step
constexpr int NSTEP = 16;             // steps per strip
constexpr int STRIP = STEP * NSTEP;   // 64 rows per block
constexpr int SLOTS = 16;             // LDS ring slots (4KB each) = 64 KB
constexpr int NSTRIP = T_ / STRIP;    // 64 strips per image
constexpr int NXCD = 8;

typedef float vfloat4 __attribute__((ext_vector_type(4)));
typedef const __attribute__((address_space(1))) unsigned int* gp_t;
typedef __attribute__((address_space(3))) unsigned int* lp_t;

__global__ __launch_bounds__(256, 2) void lwconv_kernel(
    const float* __restrict__ x, const float* __restrict__ w,
    float* __restrict__ y) {
  __shared__ float xs[SLOTS][C_];     // 16 x 4KB ring
  const int tid = threadIdx.x;
  const int wq  = tid >> 6;           // wave 0..3: owns channels [wq*256, +256)

  // Per-thread softmax for this thread's 4 heads (L1-broadcast loads; no LDS).
  const int h0 = (4 * tid) & (H_ - 1);
  float wr[4][K_];
#pragma unroll
  for (int j = 0; j < 4; ++j) {
    const int h = h0 + j;             // <= 15 (4 | 16, never wraps)
    float v[K_];
    float m = -1e30f;
#pragma unroll
    for (int k = 0; k < K_; ++k) { v[k] = w[h * K_ + k]; m = fmaxf(m, v[k]); }
    float s = 0.f;
#pragma unroll
    for (int k = 0; k < K_; ++k) { v[k] = expf(v[k] - m); s += v[k]; }
    const float inv = 1.f / s;
#pragma unroll
    for (int k = 0; k < K_; ++k) wr[j][k] = v[k] * inv;
  }

  // XCD-aware remap: XCD i owns wids [i*64,(i+1)*64) = all 64 strips of image
  // b=i, t-ascending -> adjacent strips (sharing 6-row halo) on same XCD's L2.
  const int cpx = (B_ * NSTRIP) / NXCD;   // 64
  const int wid = ((int)blockIdx.x % NXCD) * cpx + (int)blockIdx.x / NXCD;
  const int b  = wid / NSTRIP;
  const int t0 = (wid % NSTRIP) * STRIP;  // multiple of 64 -> t0 % 16 == 0

  const float* xg = x + (size_t)b * T_ * C_ + 4 * tid;  // lane's 16B column
  float*       yg = y + (size_t)b * T_ * C_ + 4 * tid;
  const vfloat4 z4 = {0.f, 0.f, 0.f, 0.f};

  // Stage relative row d (absolute t0+d) into slot d&15, this wave's quarter.
  // Address CLAMPED (not skipped) so every step issues exactly 4 VMEM loads
  // and the counted vmcnt stays exact; OOB slots are zero-fixed post-wait.
  auto STAGE = [&](int d) {
    int t = t0 + d;
    t = t < 0 ? 0 : (t >= T_ ? T_ - 1 : t);
    __builtin_amdgcn_global_load_lds((gp_t)(xg + (size_t)t * C_),
                                     (lp_t)&xs[d & 15][wq * 256], 16, 0, 0);
  };
  // Overwrite an OOB row's slot with zeros (wave-private 16B per lane).
  auto ZFIX = [&](int d) {
    const int t = t0 + d;             // wave-uniform test -> scalar branch
    if (t < 0 || t >= T_)
      *reinterpret_cast<vfloat4*>(&xs[d & 15][4 * tid]) = z4;
  };

  // Prologue: rows -3..+6 (10 loads), one-time full drain, fix t<0 slots.
#pragma unroll
  for (int d = -PAD_; d <= 6; ++d) STAGE(d);
  asm volatile("s_waitcnt vmcnt(0)" ::: "memory");
  __builtin_amdgcn_sched_barrier(0);
#pragma unroll
  for (int d = -PAD_; d < 0; ++d) ZFIX(d);  // d>=0 prologue rows always valid

#pragma unroll
  for (int j = 0; j < NSTEP; ++j) {
    const int r0 = STEP * j;          // relative output row of this step

    // Issue next step's 4 rows; they drain under THIS step's compute.
    STAGE(r0 + 7); STAGE(r0 + 8); STAGE(r0 + 9); STAGE(r0 + 10);

    // Outstanding (newest first): 4 loads just issued + 4 nt-stores from the
    // previous step = 8; everything older (incl. this step's input rows,
    // staged last step) retired. Never drains to 0.
    asm volatile("s_waitcnt vmcnt(8)" ::: "memory");
    __builtin_amdgcn_sched_barrier(0);

    // Rows staged last step that this step reads: r0+3..r0+6 (tail of image
    // may be OOB -> zero them now that their loads retired).
    ZFIX(r0 + 3); ZFIX(r0 + 4); ZFIX(r0 + 5); ZFIX(r0 + 6);

    // Read the 10 live input rows once, FMA 4 output rows from them.
    vfloat4 v[10];
#pragma unroll
    for (int i = 0; i < 10; ++i)
      v[i] = *reinterpret_cast<const vfloat4*>(
          &xs[(r0 - PAD_ + i) & 15][4 * tid]);

#pragma unroll
    for (int q = 0; q < STEP; ++q) {
      float ax = 0.f, ay = 0.f, az = 0.f, aw = 0.f;
#pragma unroll
      for (int k = 0; k < K_; ++k) {
        const vfloat4 t4 = v[q + k];
        ax = fmaf(t4.x, wr[0][k], ax);
        ay = fmaf(t4.y, wr[1][k], ay);
        az = fmaf(t4.z, wr[2][k], az);
        aw = fmaf(t4.w, wr[3][k], aw);
      }
      vfloat4 o;
      o.x = ax; o.y = ay; o.z = az; o.w = aw;
      // y never read: nt store keeps x resident in L2/L3.
      __builtin_nontemporal_store(
          o, reinterpret_cast<vfloat4*>(yg + (size_t)(t0 + r0 + q) * C_));
    }
  }
}

extern "C" void kernel_launch(void* const* d_in, const int* in_sizes, int n_in,
                              void* d_out, int out_size, void* d_ws, size_t ws_size,
                              hipStream_t stream) {
  const float* x = (const float*)d_in[0];   // (B,T,C) fp32
  const float* w = (const float*)d_in[1];   // (H,1,K) fp32
  float* y = (float*)d_out;                 // (B,T,C) fp32

  const int grid = B_ * NSTRIP;             // 512 blocks = 2 per CU
  lwconv_kernel<<<grid, 256, 0, stream>>>(x, w, y);
}

// Round 9
// 230.133 us; speedup vs baseline: 1.0311x; 1.0311x over previous
//
#include <hip/hip_runtime.h>

// LightweightConv1d: y[b,t,c] = sum_k softmax(w)[c%H,k] * x[b, t+k-PAD, c]
// x: (B,T,C) fp32 contiguous (C innermost), w: (H,1,K) fp32, y: (B,T,C) fp32.
// History (conv dispatch): R2 ~71-77 / R5 80.7 / R6 97 / R7 85.6 / R9 ~77 /
//   R10 83.4. Theories killed: occupancy (R5: 76% occ, same), MLP depth
//   (R9: provable depth-14 LDS staging, same), burst convoy (R10: counted
//   vmcnt, never-drain ring, same-or-worse). Surviving model: per-CU read-
//   miss CONCURRENCY cap (~64 lines x 64B / ~400ns ~= 2.6-3.2 TB/s chip-wide
//   logical read service; our best kernels sit exactly at the m13-copy
//   read-side ceiling of ~3.15 TB/s). Only remaining lever: LOGICAL READ
//   VOLUME (amp). R10 cut amp to 1.09 but its throttled ring issued lines
//   at 1.76 TB/s and lost; R11 cuts amp with the PROVEN R9 burst structure.
// R11: TCHUNK=16 x half-C blocks. 256 threads stage a 22-row x 512-ch window
//   (44 KB LDS -> 3 blocks/CU co-resident, convoy overlap > R9's 2);
//   11 back-to-back global_load_lds per wave; single vmcnt(0)+barrier drain
//   (proven correct); 8 outputs/thread. Logical reads 229 -> 184 MB
//   (amp 1.75 -> 1.375). Keep XCD remap + nt stores + reg softmax.
// Pre-commit: conv >= 75us here => amp lever dead => declare roofline.

constexpr int B_   = 8;
constexpr int T_   = 4096;
constexpr int C_   = 1024;
constexpr int H_   = 16;
constexpr int K_   = 7;
constexpr int PAD_ = 3;
constexpr int TCHUNK = 16;            // output rows per block
constexpr int W_  = TCHUNK + K_ - 1;  // 22 window rows
constexpr int CSPLIT = 2;
constexpr int CH  = C_ / CSPLIT;      // 512 channels per block
constexpr int NCHUNK = T_ / TCHUNK;   // 256 chunks per image-half
constexpr int NXCD = 8;

typedef float vfloat4 __attribute__((ext_vector_type(4)));
typedef const __attribute__((address_space(1))) unsigned int* gp_t;
typedef __attribute__((address_space(3))) unsigned int* lp_t;

__global__ __launch_bounds__(256, 3) void lwconv_kernel(
    const float* __restrict__ x, const float* __restrict__ w,
    float* __restrict__ y) {
  __shared__ float xs[W_][CH];        // 22 x 2KB = 44 KB -> 3 blocks/CU
  const int tid  = threadIdx.x;
  const int wave = tid >> 6;          // 0..3
  const int lane = tid & 63;
  const int rr   = tid >> 7;          // 0/1: which 8-row half this thread computes
  const int c4i  = tid & 127;         // float4 index within 512-ch slab

  // Per-thread softmax for this thread's 4 heads (L1-broadcast loads, no LDS).
  const int h0 = (4 * c4i) & (H_ - 1);   // == (4*tid)&15, chalf*512 % 16 == 0
  float wr[4][K_];
#pragma unroll
  for (int j = 0; j < 4; ++j) {
    const int h = h0 + j;             // <= 15 (4 | 16, never wraps)
    float v[K_];
    float m = -1e30f;
#pragma unroll
    for (int k = 0; k < K_; ++k) { v[k] = w[h * K_ + k]; m = fmaxf(m, v[k]); }
    float s = 0.f;
#pragma unroll
    for (int k = 0; k < K_; ++k) { v[k] = expf(v[k] - m); s += v[k]; }
    const float inv = 1.f / s;
#pragma unroll
    for (int k = 0; k < K_; ++k) wr[j][k] = v[k] * inv;
  }

  // XCD-aware remap: grid 4096, cpx 512 -> XCD i owns 2 image-halves,
  // t-ascending (consecutive wids share the 6-row halo -> same-XCD L2 hits).
  const int cpx = (B_ * CSPLIT * NCHUNK) / NXCD;   // 512
  const int wid = ((int)blockIdx.x % NXCD) * cpx + (int)blockIdx.x / NXCD;
  const int pair  = wid / NCHUNK;          // 0..15
  const int tc    = wid % NCHUNK;
  const int b     = pair & (B_ - 1);
  const int chalf = pair >> 3;             // 0/1
  const int t0    = tc * TCHUNK;

  const float* xb = x + (size_t)b * T_ * C_ + chalf * CH;  // block's slab base
  float*       yb = y + (size_t)b * T_ * C_ + chalf * CH;

  // Pre-zero OOB window rows (t<0 at t0==0; t>=T at t0==T-16). 512 floats per
  // row / 256 threads = one float2 each; ordered by the barrier below.
  if (t0 == 0) {
#pragma unroll
    for (int i = 0; i < PAD_; ++i)
      *reinterpret_cast<float2*>(&xs[i][2 * tid]) = make_float2(0.f, 0.f);
  }
  if (t0 == T_ - TCHUNK) {
#pragma unroll
    for (int i = W_ - PAD_; i < W_; ++i)
      *reinterpret_cast<float2*>(&xs[i][2 * tid]) = make_float2(0.f, 0.f);
  }

  // Stage the 22x512 window: 44 half-row (1KB) ops, 11 per wave, issued
  // back-to-back (LDS destinations -> nothing for the compiler to strip-mine).
#pragma unroll
  for (int j = 0; j < 11; ++j) {
    const int l    = wave * 11 + j;       // 0..43, wave-uniform
    const int row  = l >> 1;              // 0..21
    const int half = l & 1;
    const int t    = t0 - PAD_ + row;     // wave-uniform bounds test
    if (t >= 0 && t < T_) {
      __builtin_amdgcn_global_load_lds(
          (gp_t)(xb + (size_t)t * C_ + half * 256 + 4 * lane),
          (lp_t)&xs[row][half * 256], 16, 0, 0);
    }
  }

  asm volatile("s_waitcnt vmcnt(0)" ::: "memory");
  __syncthreads();

  // Thread (rr, c4i) computes 8 output rows g = t0 + rr*8 + q, q=0..7.
  // Inputs for q: window rows rr*8+q .. rr*8+q+6 (max 21, in range).
#pragma unroll
  for (int q = 0; q < 8; ++q) {
    const int wr0 = rr * 8 + q;
    float ax = 0.f, ay = 0.f, az = 0.f, aw = 0.f;
#pragma unroll
    for (int k = 0; k < K_; ++k) {
      const float4 v = *reinterpret_cast<const float4*>(&xs[wr0 + k][4 * c4i]);
      ax = fmaf(v.x, wr[0][k], ax);
      ay = fmaf(v.y, wr[1][k], ay);
      az = fmaf(v.z, wr[2][k], az);
      aw = fmaf(v.w, wr[3][k], aw);
    }
    vfloat4 o;
    o.x = ax; o.y = ay; o.z = az; o.w = aw;
    // y never read: nt store keeps x resident in L2/L3.
    __builtin_nontemporal_store(
        o, reinterpret_cast<vfloat4*>(yb + (size_t)(t0 + wr0) * C_ + 4 * c4i));
  }
}

extern "C" void kernel_launch(void* const* d_in, const int* in_sizes, int n_in,
                              void* d_out, int out_size, void* d_ws, size_t ws_size,
                              hipStream_t stream) {
  const float* x = (const float*)d_in[0];   // (B,T,C) fp32
  const float* w = (const float*)d_in[1];   // (H,1,K) fp32
  float* y = (float*)d_out;                 // (B,T,C) fp32

  const int grid = B_ * CSPLIT * NCHUNK;    // 4096 blocks
  lwconv_kernel<<<grid, 256, 0, stream>>>(x, w, y);
}